// Round 17
// baseline (83.553 us; speedup 1.0000x reference)
//
#include <hip/hip_runtime.h>
#include <math.h>

// Problem constants
#define NB 2
#define NC 19      // classes
#define NH 128
#define NW 128
#define NCF 64     // feature channels
#define NHE 64     // ema logits H/W
#define NHX 32     // x_ema H/W
#define EPSC 1e-8f

// d_ws: acc[0..2] (64B pad) | cn[2048] f32
#define WS_CN_OFF 64

__global__ void pfst_init(float* __restrict__ acc) {
    acc[0] = 0.f; acc[1] = 0.f; acc[2] = 0.f;
}

// Cell norms: cn[b*1024+pos] = sum_c xe[b,c,pos]^2
__global__ __launch_bounds__(256) void pfst_norm(const float* __restrict__ xe,
                                                 float* __restrict__ cn) {
    int idx = blockIdx.x * 256 + threadIdx.x;    // < 2048
    int b = idx >> 10, pos = idx & 1023;
    const float* X = xe + b * (NCF * 1024) + pos;
    float s = 0.f;
    #pragma unroll
    for (int c = 0; c < NCF; c++) { float v = X[c * 1024]; s = fmaf(v, v, s); }
    cn[idx] = s;
}

__device__ __forceinline__ int clampi(int v, int lo, int hi) {
    return v < lo ? lo : (v > hi ? hi : v);
}

// 8 lanes/pixel. Lanes 0-3: pos selection+softmax (classes (l&3)+4jc);
// lanes 4-7: neg (scan on -sims — IEEE-exact mirror of top_k(-sim)).
// Block = 32 consecutive-w pixels (same b,h); LDS-staged ema/xe/cn tiles.
__global__ __launch_bounds__(256) void pfst_main(
    const float* __restrict__ trg, const float* __restrict__ ema,
    const float* __restrict__ xe,  const float* __restrict__ mix,
    const float* __restrict__ cn,  float* __restrict__ acc)
{
    __shared__ float se[NC * 193];        // ema tile [19][8][24], stride 193
    __shared__ float sx[NCF * 49];        // xe tile [64][4][12], stride 49
    __shared__ float scn[48];             // cn tile [4][12]
    __shared__ float red[4][3];

    int tid = threadIdx.x;
    int l = tid & 7;                      // lane in octet
    int lc = l & 3;                       // class-lane within half
    int q = tid >> 3;                     // pixel slot (0..31)
    int p0 = blockIdx.x * 32;
    int b = p0 >> 14;
    int h = (p0 >> 7) & 127;              // block-uniform
    int w0 = p0 & 127;                    // multiple of 32
    int w = w0 + q;

    int ey0 = (h - 7) >> 1, ex0 = (w0 - 7) >> 1;   // ema tile origin
    int by0 = (h - 6) >> 2, bx0 = (w0 - 6) >> 2;   // cell tile origin

    // ---------- Stage tiles (all threads, before divergence) ----------
    {
        const float* Eb = ema + b * NC * (NHE * NHE);
        for (int idx = tid; idx < NC * 8 * 24; idx += 256) {
            int c = idx / 192; int rr = idx - c * 192;
            int r = rr / 24;   int x = rr - r * 24;
            int gy = clampi(ey0 + r, 0, 63), gx = clampi(ex0 + x, 0, 63);
            se[c * 193 + rr] = Eb[c * (NHE * NHE) + gy * 64 + gx];
        }
        const float* Xb = xe + b * (NCF * NHX * NHX);
        for (int idx = tid; idx < NCF * 48; idx += 256) {
            int ch = idx / 48; int rr = idx - ch * 48;
            int a = rr / 12;   int d = rr - a * 12;
            int gy = clampi(by0 + a, 0, 31), gx = clampi(bx0 + d, 0, 31);
            sx[ch * 49 + rr] = Xb[ch * (NHX * NHX) + gy * 32 + gx];
        }
        const float* CNb = cn + (b << 10);
        if (tid < 48) {
            int a = tid / 12, d = tid - a * 12;
            int gy = clampi(by0 + a, 0, 31), gx = clampi(bx0 + d, 0, 31);
            scn[tid] = CNb[gy * 32 + gx];
        }
    }
    __syncthreads();

    float mval = mix[(b << 14) + (h << 7) + w];
    bool active = mval < 0.5f;            // (1 - mix) > 0.5
    float lp = 0.f, ln = 0.f;
    float cm = (active && l == 0) ? 1.f : 0.f;

    if (active) {
        // ---------- Phase 1: cell dots from LDS, 8 channels/lane ----------
        int bx = (w - 6) >> 2;
        int trow[4], tcol[4];
        #pragma unroll
        for (int a = 0; a < 4; a++) trow[a] = clampi(by0 + a, 0, 31) - by0;
        #pragma unroll
        for (int d = 0; d < 4; d++) tcol[d] = clampi(bx + d, 0, 31) - bx0;
        int coffT = ((h >> 2) - by0) * 12 + ((w >> 2) - bx0);

        float dotc[16];
        #pragma unroll
        for (int e = 0; e < 16; e++) dotc[e] = 0.f;

        #pragma unroll
        for (int cc = 0; cc < 8; cc++) {
            const float* Sx = sx + (l * 8 + cc) * 49;
            float cv = Sx[coffT];
            #pragma unroll
            for (int a = 0; a < 4; a++) {
                int rb = trow[a] * 12;
                #pragma unroll
                for (int d = 0; d < 4; d++)
                    dotc[a * 4 + d] = fmaf(Sx[rb + tcol[d]], cv, dotc[a * 4 + d]);
            }
        }
        #pragma unroll
        for (int e = 0; e < 16; e++) {
            dotc[e] += __shfl_xor(dotc[e], 1);
            dotc[e] += __shfl_xor(dotc[e], 2);
            dotc[e] += __shfl_xor(dotc[e], 4);
        }

        float nc2 = 1.f / fmaxf(sqrtf(scn[coffT]), EPSC);
        float scell[16];
        #pragma unroll
        for (int a = 0; a < 4; a++) {
            #pragma unroll
            for (int d = 0; d < 4; d++) {
                float nu = fmaxf(sqrtf(scn[trow[a] * 12 + tcol[d]]), EPSC);
                scell[a * 4 + d] = dotc[a * 4 + d] * nc2 / nu;
            }
        }

        // ---------- Phase 2: 49 sims; neg half stores NEGATED values ----------
        const int QA[7] = {0, 0, 1, 1, 2, 2, 3};
        const int QB[7] = {0, 1, 1, 2, 2, 3, 3};
        bool ry = (h & 3) >= 2, rx = (w & 3) >= 2;
        bool posH = (l < 4);

        float sims[49];
        #pragma unroll
        for (int i = 0; i < 7; i++) {
            int py = h + 2 * i - 6;
            bool vy = (unsigned)py < 128u;
            float srow[4];
            #pragma unroll
            for (int d = 0; d < 4; d++)
                srow[d] = ry ? scell[QA[i] * 4 + d] : scell[QB[i] * 4 + d];
            #pragma unroll
            for (int j = 0; j < 7; j++) {
                int px = w + 2 * j - 6;
                bool vx = (unsigned)px < 128u;
                float v = rx ? srow[QA[j]] : srow[QB[j]];
                float sv = (vy && vx) ? v : 0.f;
                sims[i * 7 + j] = posH ? sv : -sv;
            }
        }

        // ---------- Phase 3: 9-round strict-> scan (proven tie semantics) ------
        // pos half: top-9 of sims. neg half: top-9 of -sims == bottom-9;
        // round 9 discarded for neg (reference takes bottom-8).
        float vsel[9]; int isel[9];
        {
            unsigned lo = 0u, hi = 0u;
            #pragma unroll
            for (int t = 0; t < 9; t++) {
                float best = -3.4e38f; int bi = 0;
                #pragma unroll
                for (int k = 0; k < 49; k++) {
                    bool freek = (k < 32) ? !((lo >> k) & 1u) : !((hi >> (k - 32)) & 1u);
                    if (freek && sims[k] > best) { best = sims[k]; bi = k; }
                }
                vsel[t] = best; isel[t] = bi;
                if (bi < 32) lo |= 1u << bi; else hi |= 1u << (bi - 32);
            }
        }

        // ---------- Phase 4: gather from LDS ema tile ----------
        float av[5];
        #pragma unroll
        for (int jc = 0; jc < 5; jc++) av[jc] = 0.f;

        #pragma unroll
        for (int t = 0; t < 9; t++) {
            if (posH || t < 8) {
                int k = isel[t];
                float val = posH ? vsel[t] : -vsel[t];
                int i = (k * 586) >> 12; int j = k - 7 * i;
                int py = h + 2 * i - 6, px = w + 2 * j - 6;
                if ((unsigned)py < 128u && (unsigned)px < 128u) {
                    int iy0 = (py - 1) >> 1; float ty = (py & 1) ? 0.25f : 0.75f;
                    int ix0 = (px - 1) >> 1; float tx = (px & 1) ? 0.25f : 0.75f;
                    int y0 = clampi(iy0, 0, 63), y1 = clampi(iy0 + 1, 0, 63);
                    int x0 = clampi(ix0, 0, 63), x1 = clampi(ix0 + 1, 0, 63);
                    float w00 = (1.f - ty) * (1.f - tx), w01 = (1.f - ty) * tx;
                    float w10 = ty * (1.f - tx),         w11 = ty * tx;
                    int o00 = (y0 - ey0) * 24 + (x0 - ex0), o01 = (y0 - ey0) * 24 + (x1 - ex0);
                    int o10 = (y1 - ey0) * 24 + (x0 - ex0), o11 = (y1 - ey0) * 24 + (x1 - ex0);
                    #pragma unroll
                    for (int jc = 0; jc < 5; jc++) {
                        int c = lc + 4 * jc;
                        if (c < NC) {
                            const float* Sc = se + c * 193;
                            float g = w00 * Sc[o00] + w01 * Sc[o01]
                                    + w10 * Sc[o10] + w11 * Sc[o11];
                            av[jc] = fmaf(val, g, av[jc]);
                        }
                    }
                }
            }
        }

        // ---------- Phase 5: softmax + BCE within each half ----------
        float m = -3.4e38f;
        #pragma unroll
        for (int jc = 0; jc < 5; jc++) {
            int c = lc + 4 * jc;
            if (c < NC) m = fmaxf(m, av[jc]);
        }
        m = fmaxf(m, __shfl_xor(m, 1)); m = fmaxf(m, __shfl_xor(m, 2));

        float Z = 0.f, S = 0.f, Bs = 0.f;
        const float* Tb = trg + b * NC * (NH * NW) + (h << 7) + w;
        #pragma unroll
        for (int jc = 0; jc < 5; jc++) {
            int c = lc + 4 * jc;
            if (c < NC) {
                float x = Tb[c * (NH * NW)];
                float e = expf(av[jc] - m); Z += e; S += e * x;
                float ls = fminf(x, 0.f) - log1pf(expf(-fabsf(x)));  // log_sigmoid
                Bs += x - ls;
            }
        }
        #pragma unroll
        for (int s = 1; s <= 2; s <<= 1) {
            Z += __shfl_xor(Z, s); S += __shfl_xor(S, s); Bs += __shfl_xor(Bs, s);
        }
        float res = posH ? (Bs - S / Z) : (S / Z - Bs);
        lp = (l == 0) ? res : 0.f;        // sum_c bce(x, pl_pos)
        ln = (l == 4) ? res : 0.f;        // sum_c -bce(x, pl_neg)
    }

    // ---------- Wave reduce, block reduce, atomics ----------
    #pragma unroll
    for (int off = 32; off > 0; off >>= 1) {
        lp += __shfl_down(lp, off);
        ln += __shfl_down(ln, off);
        cm += __shfl_down(cm, off);
    }
    int wid = tid >> 6;
    if ((tid & 63) == 0) { red[wid][0] = lp; red[wid][1] = ln; red[wid][2] = cm; }
    __syncthreads();
    if (tid == 0) {
        atomicAdd(acc + 0, red[0][0] + red[1][0] + red[2][0] + red[3][0]);
        atomicAdd(acc + 1, red[0][1] + red[1][1] + red[2][1] + red[3][1]);
        atomicAdd(acc + 2, red[0][2] + red[1][2] + red[2][2] + red[3][2]);
    }
}

// Output: FLOAT32[2] = [loss_pos, 0.1*loss_neg] (decoded R0-R10, verified R11+).
__global__ void pfst_final(const float* __restrict__ acc, float* __restrict__ out) {
    float denom = acc[2] * (float)NC;
    out[0] = acc[0] / denom;              // loss_pos * W_POS(=1.0)
    out[1] = acc[1] / denom * 0.1f;       // loss_neg * W_NEG(=0.1)
}

extern "C" void kernel_launch(void* const* d_in, const int* in_sizes, int n_in,
                              void* d_out, int out_size, void* d_ws, size_t ws_size,
                              hipStream_t stream) {
    const float* trg = (const float*)d_in[0];   // [2,19,128,128]
    const float* ema = (const float*)d_in[1];   // [2,19,64,64]
    const float* xe  = (const float*)d_in[2];   // [2,64,32,32]
    const float* mix = (const float*)d_in[3];   // [2,1,128,128]
    float* acc = (float*)d_ws;
    float* cnw = (float*)((char*)d_ws + WS_CN_OFF);
    float* out = (float*)d_out;

    hipLaunchKernelGGL(pfst_init, dim3(1), dim3(1), 0, stream, acc);
    hipLaunchKernelGGL(pfst_norm, dim3(8), dim3(256), 0, stream, xe, cnw);
    // 8 lanes/pixel: 32 pixels per 256-thread block -> 1024 blocks.
    hipLaunchKernelGGL(pfst_main, dim3((NB * NH * NW) / 32), dim3(256), 0, stream,
                       trg, ema, xe, mix, cnw, acc);
    hipLaunchKernelGGL(pfst_final, dim3(1), dim3(1), 0, stream, acc, out);
}

// Round 18
// 79.803 us; speedup vs baseline: 1.0470x; 1.0470x over previous
//
#include <hip/hip_runtime.h>
#include <math.h>

// Problem constants
#define NB 2
#define NC 19      // classes
#define NH 128
#define NW 128
#define NCF 64     // feature channels
#define NHE 64     // ema logits H/W
#define NHX 32     // x_ema H/W
#define EPSC 1e-8f

__global__ void pfst_init(float* __restrict__ acc) {
    acc[0] = 0.f; acc[1] = 0.f; acc[2] = 0.f;
}

__device__ __forceinline__ int clampi(int v, int lo, int hi) {
    return v < lo ? lo : (v > hi ? hi : v);
}

// 4 lanes/pixel (R16 structure). LDS-staged ema/xe tiles; cell norms computed
// in-LDS from the staged xe tile (bit-identical c-order). Selection via
// order-preserving binary tree (== stable lowest-index scan, ~4x less depth).
__global__ __launch_bounds__(256) void pfst_main(
    const float* __restrict__ trg, const float* __restrict__ ema,
    const float* __restrict__ xe,  const float* __restrict__ mix,
    float* __restrict__ acc)
{
    __shared__ float se[NC * 321];        // ema tile [19][8][40], stride 321 (pad)
    __shared__ float sx[NCF * 85];        // xe tile [64][4][21], stride 85 (pad)
    __shared__ float scn[84];             // cell-norm tile [4][21]
    __shared__ float red[4][3];

    int tid = threadIdx.x;
    int l = tid & 3;                      // lane in quad
    int q = tid >> 2;                     // pixel slot (0..63)
    int p0 = blockIdx.x * 64;
    int b = p0 >> 14;
    int h = (p0 >> 7) & 127;              // block-uniform
    int w0 = p0 & 127;                    // 0 or 64
    int w = w0 + q;

    int ey0 = (h - 7) >> 1, ex0 = (w0 - 7) >> 1;   // ema tile origin
    int by0 = (h - 6) >> 2, bx0 = (w0 - 6) >> 2;   // cell tile origin

    // ---------- Stage tiles ----------
    {
        const float* Eb = ema + b * NC * (NHE * NHE);
        for (int idx = tid; idx < NC * 8 * 40; idx += 256) {
            int c = idx / 320; int rr = idx - c * 320;
            int r = rr / 40;   int x = rr - r * 40;
            int gy = clampi(ey0 + r, 0, 63), gx = clampi(ex0 + x, 0, 63);
            se[c * 321 + rr] = Eb[c * (NHE * NHE) + gy * 64 + gx];
        }
        const float* Xb = xe + b * (NCF * NHX * NHX);
        for (int idx = tid; idx < NCF * 84; idx += 256) {
            int ch = idx / 84; int rr = idx - ch * 84;
            int a = rr / 21;   int d = rr - a * 21;
            int gy = clampi(by0 + a, 0, 31), gx = clampi(bx0 + d, 0, 31);
            sx[ch * 85 + rr] = Xb[ch * (NHX * NHX) + gy * 32 + gx];
        }
    }
    __syncthreads();
    // cell norms from staged tile (same channel order as the old cn kernel)
    if (tid < 84) {
        float s = 0.f;
        #pragma unroll
        for (int ch = 0; ch < NCF; ch++) {
            float v = sx[ch * 85 + tid];
            s = fmaf(v, v, s);
        }
        scn[tid] = s;
    }
    __syncthreads();

    float mval = mix[(b << 14) + (h << 7) + w];
    bool active = mval < 0.5f;            // (1 - mix) > 0.5
    float lp = 0.f, ln = 0.f;
    float cm = (active && l == 0) ? 1.f : 0.f;

    if (active) {
        // ---------- Prefetch trg (hides under phases 1-3) ----------
        const float* Tb = trg + b * NC * (NH * NW) + (h << 7) + w;
        float tx[5];
        #pragma unroll
        for (int jc = 0; jc < 5; jc++) {
            int c = l + 4 * jc;
            tx[jc] = (c < NC) ? Tb[c * (NH * NW)] : 0.f;
        }

        // ---------- Phase 1: cell dots from LDS, 16 channels/lane ----------
        int bx = (w - 6) >> 2;
        int trow[4], tcol[4];
        #pragma unroll
        for (int a = 0; a < 4; a++) trow[a] = clampi(by0 + a, 0, 31) - by0;
        #pragma unroll
        for (int d = 0; d < 4; d++) tcol[d] = clampi(bx + d, 0, 31) - bx0;
        int coffT = ((h >> 2) - by0) * 21 + ((w >> 2) - bx0);

        float dotc[16];
        #pragma unroll
        for (int e = 0; e < 16; e++) dotc[e] = 0.f;

        #pragma unroll 4
        for (int cc = 0; cc < 16; cc++) {
            const float* Sx = sx + (l * 16 + cc) * 85;
            float cv = Sx[coffT];
            #pragma unroll
            for (int a = 0; a < 4; a++) {
                int rb = trow[a] * 21;
                #pragma unroll
                for (int d = 0; d < 4; d++)
                    dotc[a * 4 + d] = fmaf(Sx[rb + tcol[d]], cv, dotc[a * 4 + d]);
            }
        }
        #pragma unroll
        for (int e = 0; e < 16; e++) {
            dotc[e] += __shfl_xor(dotc[e], 1); dotc[e] += __shfl_xor(dotc[e], 2);
        }

        float nc2 = 1.f / fmaxf(sqrtf(scn[coffT]), EPSC);
        float scell[16];
        #pragma unroll
        for (int a = 0; a < 4; a++) {
            #pragma unroll
            for (int d = 0; d < 4; d++) {
                float nu = fmaxf(sqrtf(scn[trow[a] * 21 + tcol[d]]), EPSC);
                scell[a * 4 + d] = dotc[a * 4 + d] * nc2 / nu;
            }
        }

        // ---------- Phase 2: expand to 49 sims ----------
        const int QA[7] = {0, 0, 1, 1, 2, 2, 3};
        const int QB[7] = {0, 1, 1, 2, 2, 3, 3};
        bool ry = (h & 3) >= 2, rx = (w & 3) >= 2;

        float sims[49];
        #pragma unroll
        for (int i = 0; i < 7; i++) {
            int py = h + 2 * i - 6;
            bool vy = (unsigned)py < 128u;
            float srow[4];
            #pragma unroll
            for (int d = 0; d < 4; d++)
                srow[d] = ry ? scell[QA[i] * 4 + d] : scell[QB[i] * 4 + d];
            #pragma unroll
            for (int j = 0; j < 7; j++) {
                int px = w + 2 * j - 6;
                bool vx = (unsigned)px < 128u;
                float v = rx ? srow[QA[j]] : srow[QB[j]];
                sims[i * 7 + j] = (vy && vx) ? v : 0.f;
            }
        }

        // ---------- Phase 3: tree selection (== stable lowest-index scan) -----
        // Order-preserving tree: at every level left child's tap index < right
        // child's, so tie -> keep LEFT == lowest index, via strict compare only.
        float vpos[9]; int ipos[9];
        {
            unsigned lo = 0u, hi = 0u;
            #pragma unroll 1
            for (int t = 0; t < 9; t++) {
                float av[25]; int ai[25];
                #pragma unroll
                for (int n = 0; n < 24; n++) {
                    int ka = 2 * n, kb = 2 * n + 1;
                    float va = ((ka < 32) ? ((lo >> ka) & 1u) : ((hi >> (ka - 32)) & 1u)) ? -3.4e38f : sims[ka];
                    float vb = ((kb < 32) ? ((lo >> kb) & 1u) : ((hi >> (kb - 32)) & 1u)) ? -3.4e38f : sims[kb];
                    bool s = vb > va;
                    av[n] = s ? vb : va; ai[n] = s ? kb : ka;
                }
                av[24] = ((hi >> 16) & 1u) ? -3.4e38f : sims[48]; ai[24] = 48;
                float bv[13]; int bi[13];
                #pragma unroll
                for (int n = 0; n < 12; n++) {
                    bool s = av[2 * n + 1] > av[2 * n];
                    bv[n] = s ? av[2 * n + 1] : av[2 * n]; bi[n] = s ? ai[2 * n + 1] : ai[2 * n];
                }
                bv[12] = av[24]; bi[12] = ai[24];
                float cv[7]; int ci[7];
                #pragma unroll
                for (int n = 0; n < 6; n++) {
                    bool s = bv[2 * n + 1] > bv[2 * n];
                    cv[n] = s ? bv[2 * n + 1] : bv[2 * n]; ci[n] = s ? bi[2 * n + 1] : bi[2 * n];
                }
                cv[6] = bv[12]; ci[6] = bi[12];
                float dv[4]; int di[4];
                #pragma unroll
                for (int n = 0; n < 3; n++) {
                    bool s = cv[2 * n + 1] > cv[2 * n];
                    dv[n] = s ? cv[2 * n + 1] : cv[2 * n]; di[n] = s ? ci[2 * n + 1] : ci[2 * n];
                }
                dv[3] = cv[6]; di[3] = ci[6];
                float e0, e1; int f0, f1;
                { bool s = dv[1] > dv[0]; e0 = s ? dv[1] : dv[0]; f0 = s ? di[1] : di[0]; }
                { bool s = dv[3] > dv[2]; e1 = s ? dv[3] : dv[2]; f1 = s ? di[3] : di[2]; }
                bool s = e1 > e0;
                float best = s ? e1 : e0; int bidx = s ? f1 : f0;
                vpos[t] = best; ipos[t] = bidx;
                if (bidx < 32) lo |= 1u << bidx; else hi |= 1u << (bidx - 32);
            }
        }
        float vneg[8]; int ineg[8];
        {
            unsigned lo = 0u, hi = 0u;
            #pragma unroll 1
            for (int t = 0; t < 8; t++) {
                float av[25]; int ai[25];
                #pragma unroll
                for (int n = 0; n < 24; n++) {
                    int ka = 2 * n, kb = 2 * n + 1;
                    float va = ((ka < 32) ? ((lo >> ka) & 1u) : ((hi >> (ka - 32)) & 1u)) ? 3.4e38f : sims[ka];
                    float vb = ((kb < 32) ? ((lo >> kb) & 1u) : ((hi >> (kb - 32)) & 1u)) ? 3.4e38f : sims[kb];
                    bool s = vb < va;
                    av[n] = s ? vb : va; ai[n] = s ? kb : ka;
                }
                av[24] = ((hi >> 16) & 1u) ? 3.4e38f : sims[48]; ai[24] = 48;
                float bv[13]; int bi[13];
                #pragma unroll
                for (int n = 0; n < 12; n++) {
                    bool s = bv[0] == bv[0] && av[2 * n + 1] < av[2 * n];  // strict <
                    bv[n] = s ? av[2 * n + 1] : av[2 * n]; bi[n] = s ? ai[2 * n + 1] : ai[2 * n];
                }
                bv[12] = av[24]; bi[12] = ai[24];
                float cv[7]; int ci[7];
                #pragma unroll
                for (int n = 0; n < 6; n++) {
                    bool s = bv[2 * n + 1] < bv[2 * n];
                    cv[n] = s ? bv[2 * n + 1] : bv[2 * n]; ci[n] = s ? bi[2 * n + 1] : bi[2 * n];
                }
                cv[6] = bv[12]; ci[6] = bi[12];
                float dv[4]; int di[4];
                #pragma unroll
                for (int n = 0; n < 3; n++) {
                    bool s = cv[2 * n + 1] < cv[2 * n];
                    dv[n] = s ? cv[2 * n + 1] : cv[2 * n]; di[n] = s ? ci[2 * n + 1] : ci[2 * n];
                }
                dv[3] = cv[6]; di[3] = ci[6];
                float e0, e1; int f0, f1;
                { bool s = dv[1] < dv[0]; e0 = s ? dv[1] : dv[0]; f0 = s ? di[1] : di[0]; }
                { bool s = dv[3] < dv[2]; e1 = s ? dv[3] : dv[2]; f1 = s ? di[3] : di[2]; }
                bool s = e1 < e0;
                float best = s ? e1 : e0; int bidx = s ? f1 : f0;
                vneg[t] = best; ineg[t] = bidx;
                if (bidx < 32) lo |= 1u << bidx; else hi |= 1u << (bidx - 32);
            }
        }

        // ---------- Phase 4: gather from LDS ema tile ----------
        float ap[5], an[5];
        #pragma unroll
        for (int jc = 0; jc < 5; jc++) { ap[jc] = 0.f; an[jc] = 0.f; }

        #pragma unroll
        for (int t = 0; t < 17; t++) {
            int k   = (t < 9) ? ipos[t] : ineg[t - 9];
            float v = (t < 9) ? vpos[t] : vneg[t - 9];
            int i = (k * 586) >> 12; int j = k - 7 * i;
            int py = h + 2 * i - 6, px = w + 2 * j - 6;
            if ((unsigned)py < 128u && (unsigned)px < 128u) {
                int iy0 = (py - 1) >> 1; float ty = (py & 1) ? 0.25f : 0.75f;
                int ix0 = (px - 1) >> 1; float txx = (px & 1) ? 0.25f : 0.75f;
                int y0 = clampi(iy0, 0, 63), y1 = clampi(iy0 + 1, 0, 63);
                int x0 = clampi(ix0, 0, 63), x1 = clampi(ix0 + 1, 0, 63);
                float w00 = (1.f - ty) * (1.f - txx), w01 = (1.f - ty) * txx;
                float w10 = ty * (1.f - txx),         w11 = ty * txx;
                int o00 = (y0 - ey0) * 40 + (x0 - ex0), o01 = (y0 - ey0) * 40 + (x1 - ex0);
                int o10 = (y1 - ey0) * 40 + (x0 - ex0), o11 = (y1 - ey0) * 40 + (x1 - ex0);
                #pragma unroll
                for (int jc = 0; jc < 5; jc++) {
                    int c = l + 4 * jc;
                    if (c < NC) {
                        const float* Sc = se + c * 321;
                        float g = w00 * Sc[o00] + w01 * Sc[o01]
                                + w10 * Sc[o10] + w11 * Sc[o11];
                        if (t < 9) ap[jc] = fmaf(v, g, ap[jc]);
                        else       an[jc] = fmaf(v, g, an[jc]);
                    }
                }
            }
        }

        // ---------- Phase 5: softmax + BCE, classes split across quad ----------
        float mp = -3.4e38f, mn = -3.4e38f;
        #pragma unroll
        for (int jc = 0; jc < 5; jc++) {
            int c = l + 4 * jc;
            if (c < NC) { mp = fmaxf(mp, ap[jc]); mn = fmaxf(mn, an[jc]); }
        }
        mp = fmaxf(mp, __shfl_xor(mp, 1)); mp = fmaxf(mp, __shfl_xor(mp, 2));
        mn = fmaxf(mn, __shfl_xor(mn, 1)); mn = fmaxf(mn, __shfl_xor(mn, 2));

        float Zp = 0.f, Sp = 0.f, Zn = 0.f, Sn = 0.f, Bs = 0.f;
        #pragma unroll
        for (int jc = 0; jc < 5; jc++) {
            int c = l + 4 * jc;
            if (c < NC) {
                float x = tx[jc];
                float ep = expf(ap[jc] - mp); Zp += ep; Sp += ep * x;
                float en = expf(an[jc] - mn); Zn += en; Sn += en * x;
                float ls = fminf(x, 0.f) - log1pf(expf(-fabsf(x)));  // log_sigmoid
                Bs += x - ls;
            }
        }
        #pragma unroll
        for (int s = 1; s <= 2; s <<= 1) {
            Zp += __shfl_xor(Zp, s); Sp += __shfl_xor(Sp, s);
            Zn += __shfl_xor(Zn, s); Sn += __shfl_xor(Sn, s);
            Bs += __shfl_xor(Bs, s);
        }
        lp = Bs - Sp / Zp;        // sum_c bce(x, pl_pos)
        ln = Sn / Zn - Bs;        // sum_c -bce(x, pl_neg)
        if (l != 0) { lp = 0.f; ln = 0.f; }   // one contribution per pixel
    }

    // ---------- Wave reduce, block reduce, atomics ----------
    #pragma unroll
    for (int off = 32; off > 0; off >>= 1) {
        lp += __shfl_down(lp, off);
        ln += __shfl_down(ln, off);
        cm += __shfl_down(cm, off);
    }
    int wid = tid >> 6;
    if ((tid & 63) == 0) { red[wid][0] = lp; red[wid][1] = ln; red[wid][2] = cm; }
    __syncthreads();
    if (tid == 0) {
        atomicAdd(acc + 0, red[0][0] + red[1][0] + red[2][0] + red[3][0]);
        atomicAdd(acc + 1, red[0][1] + red[1][1] + red[2][1] + red[3][1]);
        atomicAdd(acc + 2, red[0][2] + red[1][2] + red[2][2] + red[3][2]);
    }
}

// Output: FLOAT32[2] = [loss_pos, 0.1*loss_neg] (decoded R0-R10, verified R11+).
__global__ void pfst_final(const float* __restrict__ acc, float* __restrict__ out) {
    float denom = acc[2] * (float)NC;
    out[0] = acc[0] / denom;              // loss_pos * W_POS(=1.0)
    out[1] = acc[1] / denom * 0.1f;       // loss_neg * W_NEG(=0.1)
}

extern "C" void kernel_launch(void* const* d_in, const int* in_sizes, int n_in,
                              void* d_out, int out_size, void* d_ws, size_t ws_size,
                              hipStream_t stream) {
    const float* trg = (const float*)d_in[0];   // [2,19,128,128]
    const float* ema = (const float*)d_in[1];   // [2,19,64,64]
    const float* xe  = (const float*)d_in[2];   // [2,64,32,32]
    const float* mix = (const float*)d_in[3];   // [2,1,128,128]
    float* acc = (float*)d_ws;
    float* out = (float*)d_out;

    hipLaunchKernelGGL(pfst_init, dim3(1), dim3(1), 0, stream, acc);
    hipLaunchKernelGGL(pfst_main, dim3((NB * NH * NW) / 64), dim3(256), 0, stream,
                       trg, ema, xe, mix, acc);
    hipLaunchKernelGGL(pfst_final, dim3(1), dim3(1), 0, stream, acc, out);
}

// Round 19
// 57.441 us; speedup vs baseline: 1.4546x; 1.3893x over previous
//
#include <hip/hip_runtime.h>
#include <math.h>

// Problem constants
#define NB 2
#define NC 19      // classes
#define NH 128
#define NW 128
#define NCF 64     // feature channels
#define NHE 64     // ema logits H/W
#define NHX 32     // x_ema H/W
#define EPSC 1e-8f

// d_ws: acc[0..2] (64B pad) | cn[2048] f32
#define WS_CN_OFF 64

__global__ void pfst_init(float* __restrict__ acc) {
    acc[0] = 0.f; acc[1] = 0.f; acc[2] = 0.f;
}

// Cell norms: cn[b*1024+pos] = sum_c xe[b,c,pos]^2
__global__ __launch_bounds__(256) void pfst_norm(const float* __restrict__ xe,
                                                 float* __restrict__ cn) {
    int idx = blockIdx.x * 256 + threadIdx.x;    // < 2048
    int b = idx >> 10, pos = idx & 1023;
    const float* X = xe + b * (NCF * 1024) + pos;
    float s = 0.f;
    #pragma unroll
    for (int c = 0; c < NCF; c++) { float v = X[c * 1024]; s = fmaf(v, v, s); }
    cn[idx] = s;
}

__device__ __forceinline__ int clampi(int v, int lo, int hi) {
    return v < lo ? lo : (v > hi ? hi : v);
}

// 4 lanes/pixel (R16 structure + pos/neg pair split). Lanes 0-1: pos top-9
// (classes (l&1)+2jc); lanes 2-3: neg via scan on -sims (IEEE-exact mirror of
// top_k(-sim), proven in R17 semantically). LDS layout identical to R16.
__global__ __launch_bounds__(256) void pfst_main(
    const float* __restrict__ trg, const float* __restrict__ ema,
    const float* __restrict__ xe,  const float* __restrict__ mix,
    const float* __restrict__ cn,  float* __restrict__ acc)
{
    __shared__ float se[NC * 321];        // ema tile [19][8][40], stride 321 (pad)
    __shared__ float sx[NCF * 85];        // xe tile [64][4][21], stride 85 (pad)
    __shared__ float scn[84];             // cn tile [4][21]
    __shared__ float red[4][3];

    int tid = threadIdx.x;
    int l = tid & 3;                      // lane in quad
    int lc = l & 1;                       // class-lane within pair
    bool posH = (l < 2);                  // pair role
    int q = tid >> 2;                     // pixel slot (0..63)
    int p0 = blockIdx.x * 64;
    int b = p0 >> 14;
    int h = (p0 >> 7) & 127;              // block-uniform
    int w0 = p0 & 127;                    // 0 or 64
    int w = w0 + q;

    int ey0 = (h - 7) >> 1, ex0 = (w0 - 7) >> 1;   // ema tile origin
    int by0 = (h - 6) >> 2, bx0 = (w0 - 6) >> 2;   // cell tile origin

    // ---------- Stage tiles (all threads, before any divergence) ----------
    {
        const float* Eb = ema + b * NC * (NHE * NHE);
        for (int idx = tid; idx < NC * 8 * 40; idx += 256) {
            int c = idx / 320; int rr = idx - c * 320;
            int r = rr / 40;   int x = rr - r * 40;
            int gy = clampi(ey0 + r, 0, 63), gx = clampi(ex0 + x, 0, 63);
            se[c * 321 + rr] = Eb[c * (NHE * NHE) + gy * 64 + gx];
        }
        const float* Xb = xe + b * (NCF * NHX * NHX);
        for (int idx = tid; idx < NCF * 84; idx += 256) {
            int ch = idx / 84; int rr = idx - ch * 84;
            int a = rr / 21;   int d = rr - a * 21;
            int gy = clampi(by0 + a, 0, 31), gx = clampi(bx0 + d, 0, 31);
            sx[ch * 85 + rr] = Xb[ch * (NHX * NHX) + gy * 32 + gx];
        }
        const float* CNb = cn + (b << 10);
        if (tid < 84) {
            int a = tid / 21, d = tid - a * 21;
            int gy = clampi(by0 + a, 0, 31), gx = clampi(bx0 + d, 0, 31);
            scn[tid] = CNb[gy * 32 + gx];
        }
    }
    __syncthreads();

    float mval = mix[(b << 14) + (h << 7) + w];
    bool active = mval < 0.5f;            // (1 - mix) > 0.5
    float lp = 0.f, ln = 0.f;
    float cm = (active && l == 0) ? 1.f : 0.f;

    if (active) {
        // ---------- Prefetch trg for this lane's 10 classes ----------
        const float* Tb = trg + b * NC * (NH * NW) + (h << 7) + w;
        float tx[10];
        #pragma unroll
        for (int jc = 0; jc < 10; jc++) {
            int c = lc + 2 * jc;
            tx[jc] = (c < NC) ? Tb[c * (NH * NW)] : 0.f;
        }

        // ---------- Phase 1: cell dots from LDS, 16 channels/lane ----------
        int bx = (w - 6) >> 2;
        int trow[4], tcol[4];
        #pragma unroll
        for (int a = 0; a < 4; a++) trow[a] = clampi(by0 + a, 0, 31) - by0;
        #pragma unroll
        for (int d = 0; d < 4; d++) tcol[d] = clampi(bx + d, 0, 31) - bx0;
        int coffT = ((h >> 2) - by0) * 21 + ((w >> 2) - bx0);

        float dotc[16];
        #pragma unroll
        for (int e = 0; e < 16; e++) dotc[e] = 0.f;

        #pragma unroll 4
        for (int cc = 0; cc < 16; cc++) {
            const float* Sx = sx + (l * 16 + cc) * 85;
            float cv = Sx[coffT];
            #pragma unroll
            for (int a = 0; a < 4; a++) {
                int rb = trow[a] * 21;
                #pragma unroll
                for (int d = 0; d < 4; d++)
                    dotc[a * 4 + d] = fmaf(Sx[rb + tcol[d]], cv, dotc[a * 4 + d]);
            }
        }
        #pragma unroll
        for (int e = 0; e < 16; e++) {
            dotc[e] += __shfl_xor(dotc[e], 1); dotc[e] += __shfl_xor(dotc[e], 2);
        }

        float nc2 = 1.f / fmaxf(sqrtf(scn[coffT]), EPSC);
        float scell[16];
        #pragma unroll
        for (int a = 0; a < 4; a++) {
            #pragma unroll
            for (int d = 0; d < 4; d++) {
                float nu = fmaxf(sqrtf(scn[trow[a] * 21 + tcol[d]]), EPSC);
                scell[a * 4 + d] = dotc[a * 4 + d] * nc2 / nu;
            }
        }

        // ---------- Phase 2: 49 sims; neg pair stores NEGATED values ----------
        const int QA[7] = {0, 0, 1, 1, 2, 2, 3};
        const int QB[7] = {0, 1, 1, 2, 2, 3, 3};
        bool ry = (h & 3) >= 2, rx = (w & 3) >= 2;

        float sims[49];
        #pragma unroll
        for (int i = 0; i < 7; i++) {
            int py = h + 2 * i - 6;
            bool vy = (unsigned)py < 128u;
            float srow[4];
            #pragma unroll
            for (int d = 0; d < 4; d++)
                srow[d] = ry ? scell[QA[i] * 4 + d] : scell[QB[i] * 4 + d];
            #pragma unroll
            for (int j = 0; j < 7; j++) {
                int px = w + 2 * j - 6;
                bool vx = (unsigned)px < 128u;
                float v = rx ? srow[QA[j]] : srow[QB[j]];
                float sv = (vy && vx) ? v : 0.f;
                sims[i * 7 + j] = posH ? sv : -sv;
            }
        }

        // ---------- Phase 3: 9-round strict-> scan (proven tie semantics) -----
        // pos pair: top-9 of sims; neg pair: top-9 of -sims (round 9 unused).
        float vsel[9]; int isel[9];
        {
            unsigned lo = 0u, hi = 0u;
            #pragma unroll
            for (int t = 0; t < 9; t++) {
                float best = -3.4e38f; int bi = 0;
                #pragma unroll
                for (int k = 0; k < 49; k++) {
                    bool freek = (k < 32) ? !((lo >> k) & 1u) : !((hi >> (k - 32)) & 1u);
                    if (freek && sims[k] > best) { best = sims[k]; bi = k; }
                }
                vsel[t] = best; isel[t] = bi;
                if (bi < 32) lo |= 1u << bi; else hi |= 1u << (bi - 32);
            }
        }

        // ---------- Phase 4: gather from LDS ema tile, 10 classes/lane --------
        float av[10];
        #pragma unroll
        for (int jc = 0; jc < 10; jc++) av[jc] = 0.f;

        #pragma unroll
        for (int t = 0; t < 9; t++) {
            if (posH || t < 8) {
                int k = isel[t];
                float val = posH ? vsel[t] : -vsel[t];
                int i = (k * 586) >> 12; int j = k - 7 * i;
                int py = h + 2 * i - 6, px = w + 2 * j - 6;
                if ((unsigned)py < 128u && (unsigned)px < 128u) {
                    int iy0 = (py - 1) >> 1; float ty = (py & 1) ? 0.25f : 0.75f;
                    int ix0 = (px - 1) >> 1; float txx = (px & 1) ? 0.25f : 0.75f;
                    int y0 = clampi(iy0, 0, 63), y1 = clampi(iy0 + 1, 0, 63);
                    int x0 = clampi(ix0, 0, 63), x1 = clampi(ix0 + 1, 0, 63);
                    float w00 = (1.f - ty) * (1.f - txx), w01 = (1.f - ty) * txx;
                    float w10 = ty * (1.f - txx),         w11 = ty * txx;
                    int o00 = (y0 - ey0) * 40 + (x0 - ex0), o01 = (y0 - ey0) * 40 + (x1 - ex0);
                    int o10 = (y1 - ey0) * 40 + (x0 - ex0), o11 = (y1 - ey0) * 40 + (x1 - ex0);
                    #pragma unroll
                    for (int jc = 0; jc < 10; jc++) {
                        int c = lc + 2 * jc;
                        if (c < NC) {
                            const float* Sc = se + c * 321;
                            float g = w00 * Sc[o00] + w01 * Sc[o01]
                                    + w10 * Sc[o10] + w11 * Sc[o11];
                            av[jc] = fmaf(val, g, av[jc]);
                        }
                    }
                }
            }
        }

        // ---------- Phase 5: softmax + BCE within each pair ----------
        float m = -3.4e38f;
        #pragma unroll
        for (int jc = 0; jc < 10; jc++) {
            int c = lc + 2 * jc;
            if (c < NC) m = fmaxf(m, av[jc]);
        }
        m = fmaxf(m, __shfl_xor(m, 1));

        float Z = 0.f, S = 0.f, Bs = 0.f;
        #pragma unroll
        for (int jc = 0; jc < 10; jc++) {
            int c = lc + 2 * jc;
            if (c < NC) {
                float x = tx[jc];
                float e = expf(av[jc] - m); Z += e; S += e * x;
                float ls = fminf(x, 0.f) - log1pf(expf(-fabsf(x)));  // log_sigmoid
                Bs += x - ls;
            }
        }
        Z += __shfl_xor(Z, 1); S += __shfl_xor(S, 1); Bs += __shfl_xor(Bs, 1);

        float res = posH ? (Bs - S / Z) : (S / Z - Bs);
        float oth = __shfl_xor(res, 2);       // lane 0 <- lane 2's neg result
        lp = (l == 0) ? res : 0.f;            // sum_c bce(x, pl_pos)
        ln = (l == 0) ? oth : 0.f;            // sum_c -bce(x, pl_neg)
    }

    // ---------- Wave reduce, block reduce, atomics ----------
    #pragma unroll
    for (int off = 32; off > 0; off >>= 1) {
        lp += __shfl_down(lp, off);
        ln += __shfl_down(ln, off);
        cm += __shfl_down(cm, off);
    }
    int wid = tid >> 6;
    if ((tid & 63) == 0) { red[wid][0] = lp; red[wid][1] = ln; red[wid][2] = cm; }
    __syncthreads();
    if (tid == 0) {
        atomicAdd(acc + 0, red[0][0] + red[1][0] + red[2][0] + red[3][0]);
        atomicAdd(acc + 1, red[0][1] + red[1][1] + red[2][1] + red[3][1]);
        atomicAdd(acc + 2, red[0][2] + red[1][2] + red[2][2] + red[3][2]);
    }
}

// Output: FLOAT32[2] = [loss_pos, 0.1*loss_neg] (decoded R0-R10, verified R11+).
__global__ void pfst_final(const float* __restrict__ acc, float* __restrict__ out) {
    float denom = acc[2] * (float)NC;
    out[0] = acc[0] / denom;              // loss_pos * W_POS(=1.0)
    out[1] = acc[1] / denom * 0.1f;       // loss_neg * W_NEG(=0.1)
}

extern "C" void kernel_launch(void* const* d_in, const int* in_sizes, int n_in,
                              void* d_out, int out_size, void* d_ws, size_t ws_size,
                              hipStream_t stream) {
    const float* trg = (const float*)d_in[0];   // [2,19,128,128]
    const float* ema = (const float*)d_in[1];   // [2,19,64,64]
    const float* xe  = (const float*)d_in[2];   // [2,64,32,32]
    const float* mix = (const float*)d_in[3];   // [2,1,128,128]
    float* acc = (float*)d_ws;
    float* cnw = (float*)((char*)d_ws + WS_CN_OFF);
    float* out = (float*)d_out;

    hipLaunchKernelGGL(pfst_init, dim3(1), dim3(1), 0, stream, acc);
    hipLaunchKernelGGL(pfst_norm, dim3(8), dim3(256), 0, stream, xe, cnw);
    hipLaunchKernelGGL(pfst_main, dim3((NB * NH * NW) / 64), dim3(256), 0, stream,
                       trg, ema, xe, mix, cnw, acc);
    hipLaunchKernelGGL(pfst_final, dim3(1), dim3(1), 0, stream, acc, out);
}

// Round 20
// 43.249 us; speedup vs baseline: 1.9319x; 1.3281x over previous
//
#include <hip/hip_runtime.h>
#include <math.h>

// Problem constants
#define NB 2
#define NC 19      // classes
#define NH 128
#define NW 128
#define NCF 64     // feature channels
#define NHE 64     // ema logits H/W
#define NHX 32     // x_ema H/W
#define EPSC 1e-8f
#define NBLK 512   // pfst_main grid size

// d_ws: cn[2048] f32 @64 | part[NBLK*3] f32 @8256
#define WS_CN_OFF   64
#define WS_PART_OFF (64 + 2048 * 4)

// Cell norms: cn[b*1024+pos] = sum_c xe[b,c,pos]^2
__global__ __launch_bounds__(256) void pfst_norm(const float* __restrict__ xe,
                                                 float* __restrict__ cn) {
    int idx = blockIdx.x * 256 + threadIdx.x;    // < 2048
    int b = idx >> 10, pos = idx & 1023;
    const float* X = xe + b * (NCF * 1024) + pos;
    float s = 0.f;
    #pragma unroll
    for (int c = 0; c < NCF; c++) { float v = X[c * 1024]; s = fmaf(v, v, s); }
    cn[idx] = s;
}

__device__ __forceinline__ int clampi(int v, int lo, int hi) {
    return v < lo ? lo : (v > hi ? hi : v);
}

// 4 lanes/pixel (R19 structure). Lanes 0-1: pos top-9 (classes (l&1)+2jc);
// lanes 2-3: neg via scan on -sims. NO global atomics: per-block partials.
__global__ __launch_bounds__(256) void pfst_main(
    const float* __restrict__ trg, const float* __restrict__ ema,
    const float* __restrict__ xe,  const float* __restrict__ mix,
    const float* __restrict__ cn,  float* __restrict__ part)
{
    __shared__ float se[NC * 321];        // ema tile [19][8][40], stride 321 (pad)
    __shared__ float sx[NCF * 85];        // xe tile [64][4][21], stride 85 (pad)
    __shared__ float scn[84];             // cn tile [4][21]
    __shared__ float red[4][3];

    int tid = threadIdx.x;
    int l = tid & 3;                      // lane in quad
    int lc = l & 1;                       // class-lane within pair
    bool posH = (l < 2);                  // pair role
    int q = tid >> 2;                     // pixel slot (0..63)
    int p0 = blockIdx.x * 64;
    int b = p0 >> 14;
    int h = (p0 >> 7) & 127;              // block-uniform
    int w0 = p0 & 127;                    // 0 or 64
    int w = w0 + q;

    int ey0 = (h - 7) >> 1, ex0 = (w0 - 7) >> 1;   // ema tile origin
    int by0 = (h - 6) >> 2, bx0 = (w0 - 6) >> 2;   // cell tile origin

    // ---------- Stage tiles (all threads, before any divergence) ----------
    {
        const float* Eb = ema + b * NC * (NHE * NHE);
        for (int idx = tid; idx < NC * 8 * 40; idx += 256) {
            int c = idx / 320; int rr = idx - c * 320;
            int r = rr / 40;   int x = rr - r * 40;
            int gy = clampi(ey0 + r, 0, 63), gx = clampi(ex0 + x, 0, 63);
            se[c * 321 + rr] = Eb[c * (NHE * NHE) + gy * 64 + gx];
        }
        const float* Xb = xe + b * (NCF * NHX * NHX);
        for (int idx = tid; idx < NCF * 84; idx += 256) {
            int ch = idx / 84; int rr = idx - ch * 84;
            int a = rr / 21;   int d = rr - a * 21;
            int gy = clampi(by0 + a, 0, 31), gx = clampi(bx0 + d, 0, 31);
            sx[ch * 85 + rr] = Xb[ch * (NHX * NHX) + gy * 32 + gx];
        }
        const float* CNb = cn + (b << 10);
        if (tid < 84) {
            int a = tid / 21, d = tid - a * 21;
            int gy = clampi(by0 + a, 0, 31), gx = clampi(bx0 + d, 0, 31);
            scn[tid] = CNb[gy * 32 + gx];
        }
    }
    __syncthreads();

    float mval = mix[(b << 14) + (h << 7) + w];
    bool active = mval < 0.5f;            // (1 - mix) > 0.5
    float lp = 0.f, ln = 0.f;
    float cm = (active && l == 0) ? 1.f : 0.f;

    if (active) {
        // ---------- Prefetch trg for this lane's 10 classes ----------
        const float* Tb = trg + b * NC * (NH * NW) + (h << 7) + w;
        float tx[10];
        #pragma unroll
        for (int jc = 0; jc < 10; jc++) {
            int c = lc + 2 * jc;
            tx[jc] = (c < NC) ? Tb[c * (NH * NW)] : 0.f;
        }

        // ---------- Phase 1: cell dots from LDS, 16 channels/lane ----------
        int bx = (w - 6) >> 2;
        int trow[4], tcol[4];
        #pragma unroll
        for (int a = 0; a < 4; a++) trow[a] = clampi(by0 + a, 0, 31) - by0;
        #pragma unroll
        for (int d = 0; d < 4; d++) tcol[d] = clampi(bx + d, 0, 31) - bx0;
        int coffT = ((h >> 2) - by0) * 21 + ((w >> 2) - bx0);

        float dotc[16];
        #pragma unroll
        for (int e = 0; e < 16; e++) dotc[e] = 0.f;

        #pragma unroll 4
        for (int cc = 0; cc < 16; cc++) {
            const float* Sx = sx + (l * 16 + cc) * 85;
            float cv = Sx[coffT];
            #pragma unroll
            for (int a = 0; a < 4; a++) {
                int rb = trow[a] * 21;
                #pragma unroll
                for (int d = 0; d < 4; d++)
                    dotc[a * 4 + d] = fmaf(Sx[rb + tcol[d]], cv, dotc[a * 4 + d]);
            }
        }
        #pragma unroll
        for (int e = 0; e < 16; e++) {
            dotc[e] += __shfl_xor(dotc[e], 1); dotc[e] += __shfl_xor(dotc[e], 2);
        }

        float nc2 = 1.f / fmaxf(sqrtf(scn[coffT]), EPSC);
        float scell[16];
        #pragma unroll
        for (int a = 0; a < 4; a++) {
            #pragma unroll
            for (int d = 0; d < 4; d++) {
                float nu = fmaxf(sqrtf(scn[trow[a] * 21 + tcol[d]]), EPSC);
                scell[a * 4 + d] = dotc[a * 4 + d] * nc2 / nu;
            }
        }

        // ---------- Phase 2: 49 sims; neg pair stores NEGATED values ----------
        const int QA[7] = {0, 0, 1, 1, 2, 2, 3};
        const int QB[7] = {0, 1, 1, 2, 2, 3, 3};
        bool ry = (h & 3) >= 2, rx = (w & 3) >= 2;

        float sims[49];
        #pragma unroll
        for (int i = 0; i < 7; i++) {
            int py = h + 2 * i - 6;
            bool vy = (unsigned)py < 128u;
            float srow[4];
            #pragma unroll
            for (int d = 0; d < 4; d++)
                srow[d] = ry ? scell[QA[i] * 4 + d] : scell[QB[i] * 4 + d];
            #pragma unroll
            for (int j = 0; j < 7; j++) {
                int px = w + 2 * j - 6;
                bool vx = (unsigned)px < 128u;
                float v = rx ? srow[QA[j]] : srow[QB[j]];
                float sv = (vy && vx) ? v : 0.f;
                sims[i * 7 + j] = posH ? sv : -sv;
            }
        }

        // ---------- Phase 3: 9-round strict-> scan (proven tie semantics) -----
        float vsel[9]; int isel[9];
        {
            unsigned lo = 0u, hi = 0u;
            #pragma unroll
            for (int t = 0; t < 9; t++) {
                float best = -3.4e38f; int bi = 0;
                #pragma unroll
                for (int k = 0; k < 49; k++) {
                    bool freek = (k < 32) ? !((lo >> k) & 1u) : !((hi >> (k - 32)) & 1u);
                    if (freek && sims[k] > best) { best = sims[k]; bi = k; }
                }
                vsel[t] = best; isel[t] = bi;
                if (bi < 32) lo |= 1u << bi; else hi |= 1u << (bi - 32);
            }
        }

        // ---------- Phase 4: gather from LDS ema tile, 10 classes/lane --------
        float av[10];
        #pragma unroll
        for (int jc = 0; jc < 10; jc++) av[jc] = 0.f;

        #pragma unroll
        for (int t = 0; t < 9; t++) {
            if (posH || t < 8) {
                int k = isel[t];
                float val = posH ? vsel[t] : -vsel[t];
                int i = (k * 586) >> 12; int j = k - 7 * i;
                int py = h + 2 * i - 6, px = w + 2 * j - 6;
                if ((unsigned)py < 128u && (unsigned)px < 128u) {
                    int iy0 = (py - 1) >> 1; float ty = (py & 1) ? 0.25f : 0.75f;
                    int ix0 = (px - 1) >> 1; float txx = (px & 1) ? 0.25f : 0.75f;
                    int y0 = clampi(iy0, 0, 63), y1 = clampi(iy0 + 1, 0, 63);
                    int x0 = clampi(ix0, 0, 63), x1 = clampi(ix0 + 1, 0, 63);
                    float w00 = (1.f - ty) * (1.f - txx), w01 = (1.f - ty) * txx;
                    float w10 = ty * (1.f - txx),         w11 = ty * txx;
                    int o00 = (y0 - ey0) * 40 + (x0 - ex0), o01 = (y0 - ey0) * 40 + (x1 - ex0);
                    int o10 = (y1 - ey0) * 40 + (x0 - ex0), o11 = (y1 - ey0) * 40 + (x1 - ex0);
                    #pragma unroll
                    for (int jc = 0; jc < 10; jc++) {
                        int c = lc + 2 * jc;
                        if (c < NC) {
                            const float* Sc = se + c * 321;
                            float g = w00 * Sc[o00] + w01 * Sc[o01]
                                    + w10 * Sc[o10] + w11 * Sc[o11];
                            av[jc] = fmaf(val, g, av[jc]);
                        }
                    }
                }
            }
        }

        // ---------- Phase 5: softmax + BCE within each pair ----------
        float m = -3.4e38f;
        #pragma unroll
        for (int jc = 0; jc < 10; jc++) {
            int c = lc + 2 * jc;
            if (c < NC) m = fmaxf(m, av[jc]);
        }
        m = fmaxf(m, __shfl_xor(m, 1));

        float Z = 0.f, S = 0.f, Bs = 0.f;
        #pragma unroll
        for (int jc = 0; jc < 10; jc++) {
            int c = lc + 2 * jc;
            if (c < NC) {
                float x = tx[jc];
                float e = expf(av[jc] - m); Z += e; S += e * x;
                float ls = fminf(x, 0.f) - log1pf(expf(-fabsf(x)));  // log_sigmoid
                Bs += x - ls;
            }
        }
        Z += __shfl_xor(Z, 1); S += __shfl_xor(S, 1); Bs += __shfl_xor(Bs, 1);

        float res = posH ? (Bs - S / Z) : (S / Z - Bs);
        float oth = __shfl_xor(res, 2);       // lane 0 <- lane 2's neg result
        lp = (l == 0) ? res : 0.f;            // sum_c bce(x, pl_pos)
        ln = (l == 0) ? oth : 0.f;            // sum_c -bce(x, pl_neg)
    }

    // ---------- Wave reduce, block reduce, per-block partial store ----------
    #pragma unroll
    for (int off = 32; off > 0; off >>= 1) {
        lp += __shfl_down(lp, off);
        ln += __shfl_down(ln, off);
        cm += __shfl_down(cm, off);
    }
    int wid = tid >> 6;
    if ((tid & 63) == 0) { red[wid][0] = lp; red[wid][1] = ln; red[wid][2] = cm; }
    __syncthreads();
    if (tid == 0) {
        float* pb = part + 3 * blockIdx.x;
        pb[0] = red[0][0] + red[1][0] + red[2][0] + red[3][0];
        pb[1] = red[0][1] + red[1][1] + red[2][1] + red[3][1];
        pb[2] = red[0][2] + red[1][2] + red[2][2] + red[3][2];
    }
}

// Final reduction of NBLK per-block partials (no atomics anywhere).
// Output: FLOAT32[2] = [loss_pos, 0.1*loss_neg] (decoded R0-R10, verified R11+).
__global__ __launch_bounds__(256) void pfst_final(const float* __restrict__ part,
                                                  float* __restrict__ out) {
    int t = threadIdx.x;
    float lp = part[3 * t + 0] + part[3 * (t + 256) + 0];
    float ln = part[3 * t + 1] + part[3 * (t + 256) + 1];
    float cm = part[3 * t + 2] + part[3 * (t + 256) + 2];
    #pragma unroll
    for (int off = 32; off > 0; off >>= 1) {
        lp += __shfl_down(lp, off);
        ln += __shfl_down(ln, off);
        cm += __shfl_down(cm, off);
    }
    __shared__ float red[4][3];
    int wid = t >> 6;
    if ((t & 63) == 0) { red[wid][0] = lp; red[wid][1] = ln; red[wid][2] = cm; }
    __syncthreads();
    if (t == 0) {
        float a0 = red[0][0] + red[1][0] + red[2][0] + red[3][0];
        float a1 = red[0][1] + red[1][1] + red[2][1] + red[3][1];
        float a2 = red[0][2] + red[1][2] + red[2][2] + red[3][2];
        float denom = a2 * (float)NC;
        out[0] = a0 / denom;              // loss_pos * W_POS(=1.0)
        out[1] = a1 / denom * 0.1f;       // loss_neg * W_NEG(=0.1)
    }
}

extern "C" void kernel_launch(void* const* d_in, const int* in_sizes, int n_in,
                              void* d_out, int out_size, void* d_ws, size_t ws_size,
                              hipStream_t stream) {
    const float* trg = (const float*)d_in[0];   // [2,19,128,128]
    const float* ema = (const float*)d_in[1];   // [2,19,64,64]
    const float* xe  = (const float*)d_in[2];   // [2,64,32,32]
    const float* mix = (const float*)d_in[3];   // [2,1,128,128]
    float* cnw  = (float*)((char*)d_ws + WS_CN_OFF);
    float* part = (float*)((char*)d_ws + WS_PART_OFF);
    float* out  = (float*)d_out;

    hipLaunchKernelGGL(pfst_norm, dim3(8), dim3(256), 0, stream, xe, cnw);
    hipLaunchKernelGGL(pfst_main, dim3(NBLK), dim3(256), 0, stream,
                       trg, ema, xe, mix, cnw, part);
    hipLaunchKernelGGL(pfst_final, dim3(1), dim3(256), 0, stream, part, out);
}